// Round 5
// baseline (25921.249 us; speedup 1.0000x reference)
//
#include <hip/hip_runtime.h>
#include <math.h>

typedef float f32x4 __attribute__((ext_vector_type(4)));

#define D       512
#define SEQ     2048
#define VOCAB   32000
#define NB      16      // scan blocks
#define RPB     32      // rows per block (512/16)
#define STPB    512     // scan threads per block
#define FSTRIDE 16      // ints per flag slot (64B line)

// agent-scope (device-coherent) accesses for cross-block communication
__device__ __forceinline__ float agent_ld(const float* p) {
    return __hip_atomic_load(p, __ATOMIC_RELAXED, __HIP_MEMORY_SCOPE_AGENT);
}
__device__ __forceinline__ void agent_st(float* p, float v) {
    __hip_atomic_store(p, v, __ATOMIC_RELAXED, __HIP_MEMORY_SCOPE_AGENT);
}
__device__ __forceinline__ int flag_ld_acq(const int* p) {
    return __hip_atomic_load(p, __ATOMIC_ACQUIRE, __HIP_MEMORY_SCOPE_AGENT);
}
__device__ __forceinline__ void flag_st_rel(int* p, int v) {
    __hip_atomic_store(p, v, __ATOMIC_RELEASE, __HIP_MEMORY_SCOPE_AGENT);
}

// ---------------------------------------------------------------------------
// zero the cross-block scratch (flags + h0 + rh); runs before the scan every
// call/replay -> deterministic regardless of buffer poison state.
// ---------------------------------------------------------------------------
__global__ void init_scratch(int* __restrict__ flags, float* __restrict__ hbuf,
                             float* __restrict__ rhbuf)
{
    const int t = threadIdx.x;            // 512 threads, 1 block
    if (t < NB * FSTRIDE) flags[t] = 0;   // 256 ints
    hbuf[t]  = 0.f;                       // h0 = 0
    rhbuf[t] = 0.f;
}

// ---------------------------------------------------------------------------
// Persistent GRU scan: 16 blocks x 512 threads. Block b owns rows
// [32b, 32b+32) of uz, ur, u (f32 in registers, 96 VGPR). Per step:
//   phase A: z,r from full h; write r*h; fence; flag; spin; fence
//   phase B: hxh from full r*h; update h rows; write h + f32 out
// ---------------------------------------------------------------------------
__global__ __launch_bounds__(STPB, 2) void scan_kernel(
    const int* __restrict__ X,
    const float* __restrict__ WZ, const float* __restrict__ UZ,
    const float* __restrict__ W,  const float* __restrict__ U,
    const float* __restrict__ WR, const float* __restrict__ UR,
    const float* __restrict__ BZ, const float* __restrict__ BR,
    const float* __restrict__ BH,
    int* __restrict__ flags, float* __restrict__ hbuf, float* __restrict__ rhbuf,
    float* __restrict__ outH)
{
    __shared__ int   idxsm[SEQ];
    __shared__ float hsm[(D / 32) * 33];   // padded (stride 33) staging of h / rh

    const int tid = threadIdx.x, b = blockIdx.x;
    const int r  = tid >> 4;          // 0..31 local row
    const int cg = tid & 15;          // 0..15 column group
    const int c0 = cg * 32;
    const int g  = b * RPB + r;       // global row 0..511

    for (int i = tid; i < SEQ; i += STPB) idxsm[i] = X[i];

    // load weight slices (f32): 3 x 32 = 96 VGPRs
    float uzw[32], urw[32], uw[32];
#pragma unroll
    for (int j = 0; j < 32; j += 4) {
        f32x4 vz = *(const f32x4*)&UZ[(size_t)g * D + c0 + j];
        f32x4 vr = *(const f32x4*)&UR[(size_t)g * D + c0 + j];
        f32x4 vu = *(const f32x4*)&U [(size_t)g * D + c0 + j];
#pragma unroll
        for (int q = 0; q < 4; ++q) {
            uzw[j + q] = vz[q];
            urw[j + q] = vr[q];
            uw [j + q] = vu[q];
        }
    }
    const float bzv = BZ[g], brv = BR[g], bhv = BH[g];
    __syncthreads();

    // embedding pipeline: current-step values in regs, prefetch next
    const int i0 = idxsm[0];
    float ezc = WZ[(size_t)i0 * D + g];
    float erc = WR[(size_t)i0 * D + g];
    float ehc = W [(size_t)i0 * D + g];

#pragma unroll 1
    for (int t = 0; t < SEQ; ++t) {
        const int tn = (t + 1 < SEQ) ? t + 1 : t;
        const int in_ = idxsm[tn];
        const float pz = WZ[(size_t)in_ * D + g];
        const float pr = WR[(size_t)in_ * D + g];
        const float ph = W [(size_t)in_ * D + g];

        // ---- phase A: stage full h into LDS ----
        if (tid < 128) {
            const int e = tid * 4;
            float v0 = agent_ld(&hbuf[e + 0]);
            float v1 = agent_ld(&hbuf[e + 1]);
            float v2 = agent_ld(&hbuf[e + 2]);
            float v3 = agent_ld(&hbuf[e + 3]);
            float* p = &hsm[(e >> 5) * 33 + (e & 31)];
            p[0] = v0; p[1] = v1; p[2] = v2; p[3] = v3;
        }
        __syncthreads();

        float az = 0.f, ar = 0.f;
#pragma unroll
        for (int j = 0; j < 32; ++j) {
            float hj = hsm[cg * 33 + j];
            az = fmaf(uzw[j], hj, az);
            ar = fmaf(urw[j], hj, ar);
        }
#pragma unroll
        for (int mk = 8; mk; mk >>= 1) {
            az += __shfl_xor(az, mk);
            ar += __shfl_xor(ar, mk);
        }
        const float hrow = hsm[b * 33 + r];   // h[g] (padded index)
        const float zz = 1.f / (1.f + expf(-(ezc + az + bzv)));
        const float rr = 1.f / (1.f + expf(-(erc + ar + brv)));
        if (cg == 0) agent_st(&rhbuf[g], rr * hrow);
        __syncthreads();
        __threadfence();                       // publish rhbuf
        if (tid == 0) flag_st_rel(&flags[b * FSTRIDE], 2 * t + 1);
        if (tid < NB) { while (flag_ld_acq(&flags[tid * FSTRIDE]) < 2 * t + 1) {} }
        __threadfence();                       // import peers' rhbuf
        __syncthreads();

        // ---- phase B: stage full r*h ----
        if (tid < 128) {
            const int e = tid * 4;
            float v0 = agent_ld(&rhbuf[e + 0]);
            float v1 = agent_ld(&rhbuf[e + 1]);
            float v2 = agent_ld(&rhbuf[e + 2]);
            float v3 = agent_ld(&rhbuf[e + 3]);
            float* p = &hsm[(e >> 5) * 33 + (e & 31)];
            p[0] = v0; p[1] = v1; p[2] = v2; p[3] = v3;
        }
        __syncthreads();

        float ah = 0.f;
#pragma unroll
        for (int j = 0; j < 32; ++j) {
            float xj = hsm[cg * 33 + j];
            ah = fmaf(uw[j], xj, ah);
        }
#pragma unroll
        for (int mk = 8; mk; mk >>= 1) ah += __shfl_xor(ah, mk);

        const float hxh  = tanhf(ehc + ah + bhv);
        const float hnew = hrow * zz + (1.f - zz) * hxh;
        if (cg == 0) {
            agent_st(&hbuf[g], hnew);
            outH[(size_t)t * D + g] = hnew;    // f32 hiddens output
        }
        __syncthreads();
        __threadfence();
        if (tid == 0) flag_st_rel(&flags[b * FSTRIDE], 2 * t + 2);
        if (tid < NB) { while (flag_ld_acq(&flags[tid * FSTRIDE]) < 2 * t + 2) {} }
        __threadfence();
        __syncthreads();

        ezc = pz; erc = pr; ehc = ph;
    }
}

// ---------------------------------------------------------------------------
// logits GEMM, plain f32 VALU. C[2048][32000] = hs * wy^T + by.
// 64x128 tile, K-transposed LDS, 256 thr; 4m x 8n outputs per thread.
// ---------------------------------------------------------------------------
#define TM 64
#define TN 128
#define TK 32

__global__ __launch_bounds__(256) void gemm_logits(
    const float* __restrict__ A,   // hs f32 [2048][512] (written by scan)
    const float* __restrict__ B,   // wy f32 [32000][512]
    const float* __restrict__ BY,  // by f32 [32000]
    float* __restrict__ C)         // logits f32 [2048][32000]
{
    __shared__ float As[TK][TM + 4];   // [32][68], K-major
    __shared__ float Bs[TK][TN + 4];   // [32][132], K-major

    const int tid = threadIdx.x;
    const int bm = blockIdx.y, bn = blockIdx.x;
    const int m0 = (tid >> 4) * 4;     // 0..60
    const int n0 = (tid & 15) * 8;     // 0..120

    // staging assignments
    const int ma = tid >> 2;           // 0..63 (A row)
    const int ka = (tid & 3) * 8;      // 0,8,16,24
    const int nb = tid >> 1;           // 0..127 (B row = vocab col)
    const int kb = (tid & 1) * 16;     // 0,16

    float acc[4][8] = {};

    for (int kt = 0; kt < D; kt += TK) {
        __syncthreads();
        {
            f32x4 va0 = *(const f32x4*)&A[(size_t)(bm * TM + ma) * D + kt + ka];
            f32x4 va1 = *(const f32x4*)&A[(size_t)(bm * TM + ma) * D + kt + ka + 4];
#pragma unroll
            for (int q = 0; q < 4; ++q) {
                As[ka + q][ma]     = va0[q];
                As[ka + 4 + q][ma] = va1[q];
            }
#pragma unroll
            for (int p = 0; p < 4; ++p) {
                f32x4 vb = *(const f32x4*)&B[(size_t)(bn * TN + nb) * D + kt + kb + p * 4];
#pragma unroll
                for (int q = 0; q < 4; ++q) Bs[kb + p * 4 + q][nb] = vb[q];
            }
        }
        __syncthreads();
#pragma unroll
        for (int k = 0; k < TK; ++k) {
            f32x4 av = *(const f32x4*)&As[k][m0];
            f32x4 b0 = *(const f32x4*)&Bs[k][n0];
            f32x4 b1 = *(const f32x4*)&Bs[k][n0 + 4];
#pragma unroll
            for (int i = 0; i < 4; ++i) {
#pragma unroll
                for (int j = 0; j < 4; ++j) {
                    acc[i][j]     = fmaf(av[i], b0[j], acc[i][j]);
                    acc[i][4 + j] = fmaf(av[i], b1[j], acc[i][4 + j]);
                }
            }
        }
    }

#pragma unroll
    for (int i = 0; i < 4; ++i) {
        const int m = bm * TM + m0 + i;
        float* crow = C + (size_t)m * VOCAB + bn * TN + n0;
        f32x4 o0, o1;
#pragma unroll
        for (int j = 0; j < 4; ++j) {
            o0[j] = acc[i][j]     + BY[bn * TN + n0 + j];
            o1[j] = acc[i][4 + j] + BY[bn * TN + n0 + 4 + j];
        }
        *(f32x4*)&crow[0] = o0;
        *(f32x4*)&crow[4] = o1;
    }
}

// ---------------------------------------------------------------------------
// in-place log-softmax per row (f32); logits tiny (|x|<=7) so no max pass.
// ---------------------------------------------------------------------------
__global__ __launch_bounds__(256) void logsoftmax_kernel(float* __restrict__ C)
{
    const int m = blockIdx.x;
    float* row = C + (size_t)m * VOCAB;
    const int tid = threadIdx.x;

    float s = 0.f;
    for (int v = tid; v < VOCAB / 4; v += 256) {
        f32x4 x = *(const f32x4*)&row[v * 4];
        s += expf(x[0]) + expf(x[1]) + expf(x[2]) + expf(x[3]);
    }
#pragma unroll
    for (int mk = 32; mk; mk >>= 1) s += __shfl_xor(s, mk);
    __shared__ float red[4];
    if ((tid & 63) == 0) red[tid >> 6] = s;
    __syncthreads();
    const float lse = logf(red[0] + red[1] + red[2] + red[3]);

    for (int v = tid; v < VOCAB / 4; v += 256) {
        f32x4 x = *(const f32x4*)&row[v * 4];
        x[0] -= lse; x[1] -= lse; x[2] -= lse; x[3] -= lse;
        *(f32x4*)&row[v * 4] = x;
    }
}

extern "C" void kernel_launch(void* const* d_in, const int* in_sizes, int n_in,
                              void* d_out, int out_size, void* d_ws, size_t ws_size,
                              hipStream_t stream)
{
    const int*   X  = (const int*)d_in[0];
    const float* wz = (const float*)d_in[1];
    const float* uz = (const float*)d_in[2];
    const float* w  = (const float*)d_in[3];
    const float* u  = (const float*)d_in[4];
    const float* wr = (const float*)d_in[5];
    const float* ur = (const float*)d_in[6];
    const float* wy = (const float*)d_in[7];
    const float* bz = (const float*)d_in[8];
    const float* br = (const float*)d_in[9];
    const float* bh = (const float*)d_in[10];
    const float* by = (const float*)d_in[11];

    float* out  = (float*)d_out;                     // outs f32 [2048][32000]
    float* outH = out + (size_t)SEQ * VOCAB;         // hiddens f32 [2048][512]

    // cross-block scratch: prefer d_ws; fall back to logits head (overwritten
    // by the GEMM later) if the workspace is unexpectedly small.
    char* scratch = (ws_size >= 8192) ? (char*)d_ws : (char*)d_out;
    int*   flags = (int*)scratch;                  // 1KB (16 x 64B lines)
    float* hbuf  = (float*)(scratch + 1024);       // 2KB
    float* rhbuf = (float*)(scratch + 3072);       // 2KB

    init_scratch<<<1, STPB, 0, stream>>>(flags, hbuf, rhbuf);

    scan_kernel<<<NB, STPB, 0, stream>>>(X, wz, uz, w, u, wr, ur, bz, br, bh,
                                         flags, hbuf, rhbuf, outH);

    dim3 ggrid(VOCAB / TN, SEQ / TM);              // (250, 32)
    gemm_logits<<<ggrid, 256, 0, stream>>>(outH, wy, by, out);

    logsoftmax_kernel<<<SEQ, 256, 0, stream>>>(out);
}

// Round 6
// 8350.498 us; speedup vs baseline: 3.1042x; 3.1042x over previous
//
#include <hip/hip_runtime.h>
#include <math.h>

typedef unsigned short u16;
typedef unsigned short us8 __attribute__((ext_vector_type(8)));
typedef short bf16x8 __attribute__((ext_vector_type(8)));
typedef float f32x4 __attribute__((ext_vector_type(4)));

#define D       512
#define SEQ     2048
#define VOCAB   32000
#define NB      16      // scan blocks
#define RPB     32      // rows per block (512/16)
#define STPB    512     // scan threads per block
#define FSTRIDE 16      // ints per flag slot (64B line)

__device__ __forceinline__ u16 f2bf(float f) {   // round-to-nearest-even
    union { float f; unsigned i; } x; x.f = f;
    unsigned r = x.i + 0x7fff + ((x.i >> 16) & 1);
    return (u16)(r >> 16);
}

// relaxed agent-scope (LLC-coherent, L2-bypass) accesses — NO cache
// maintenance. Ordering comes from __syncthreads' all-wave vmcnt(0) drain.
__device__ __forceinline__ float agent_ld(const float* p) {
    return __hip_atomic_load(p, __ATOMIC_RELAXED, __HIP_MEMORY_SCOPE_AGENT);
}
__device__ __forceinline__ void agent_st(float* p, float v) {
    __hip_atomic_store(p, v, __ATOMIC_RELAXED, __HIP_MEMORY_SCOPE_AGENT);
}
__device__ __forceinline__ int flag_ld(const int* p) {
    return __hip_atomic_load(p, __ATOMIC_RELAXED, __HIP_MEMORY_SCOPE_AGENT);
}
__device__ __forceinline__ void flag_st(int* p, int v) {
    __hip_atomic_store(p, v, __ATOMIC_RELAXED, __HIP_MEMORY_SCOPE_AGENT);
}

// ---------------------------------------------------------------------------
// zero the cross-block scratch; runs before the scan on every call/replay.
// ---------------------------------------------------------------------------
__global__ void init_scratch(int* __restrict__ flags, float* __restrict__ hbuf,
                             float* __restrict__ rhbuf)
{
    const int t = threadIdx.x;            // 512 threads, 1 block
    if (t < NB * FSTRIDE) flags[t] = 0;   // 256 ints
    hbuf[t]  = 0.f;                       // h0 = 0
    rhbuf[t] = 0.f;
}

// ---------------------------------------------------------------------------
// Persistent GRU scan: 16 blocks x 512 threads. Block b owns rows
// [32b, 32b+32) of uz, ur, u (f32 in registers, 96 VGPR). Per step:
//   phase A: z,r from full h; write r*h (relaxed LLC); barrier; flag; spin
//   phase B: hxh from full r*h; update h rows; write h (LLC) + f32 out
// Protocol soundness: __syncthreads() drains vmcnt(0) in EVERY wave before
// s_barrier, so all agent_st data is LLC-visible before tid0's flag store.
// ---------------------------------------------------------------------------
__global__ __launch_bounds__(STPB, 2) void scan_kernel(
    const int* __restrict__ X,
    const float* __restrict__ WZ, const float* __restrict__ UZ,
    const float* __restrict__ W,  const float* __restrict__ U,
    const float* __restrict__ WR, const float* __restrict__ UR,
    const float* __restrict__ BZ, const float* __restrict__ BR,
    const float* __restrict__ BH,
    int* __restrict__ flags, float* __restrict__ hbuf, float* __restrict__ rhbuf,
    float* __restrict__ outH)
{
    __shared__ int   idxsm[SEQ];
    __shared__ float hsm[(D / 32) * 33];   // padded (stride 33) staging of h / rh

    const int tid = threadIdx.x, b = blockIdx.x;
    const int r  = tid >> 4;          // 0..31 local row
    const int cg = tid & 15;          // 0..15 column group
    const int c0 = cg * 32;
    const int g  = b * RPB + r;       // global row 0..511

    for (int i = tid; i < SEQ; i += STPB) idxsm[i] = X[i];

    // load weight slices (f32): 3 x 32 = 96 VGPRs
    float uzw[32], urw[32], uw[32];
#pragma unroll
    for (int j = 0; j < 32; j += 4) {
        f32x4 vz = *(const f32x4*)&UZ[(size_t)g * D + c0 + j];
        f32x4 vr = *(const f32x4*)&UR[(size_t)g * D + c0 + j];
        f32x4 vu = *(const f32x4*)&U [(size_t)g * D + c0 + j];
#pragma unroll
        for (int q = 0; q < 4; ++q) {
            uzw[j + q] = vz[q];
            urw[j + q] = vr[q];
            uw [j + q] = vu[q];
        }
    }
    const float bzv = BZ[g], brv = BR[g], bhv = BH[g];
    __syncthreads();

    // embedding pipeline: current-step values in regs, prefetch next
    const int i0 = idxsm[0];
    float ezc = WZ[(size_t)i0 * D + g];
    float erc = WR[(size_t)i0 * D + g];
    float ehc = W [(size_t)i0 * D + g];

#pragma unroll 1
    for (int t = 0; t < SEQ; ++t) {
        const int tn = (t + 1 < SEQ) ? t + 1 : t;
        const int in_ = idxsm[tn];
        const float pz = WZ[(size_t)in_ * D + g];
        const float pr = WR[(size_t)in_ * D + g];
        const float ph = W [(size_t)in_ * D + g];

        // ---- phase A: stage full h into LDS (relaxed LLC loads) ----
        if (tid < 128) {
            const int e = tid * 4;
            float v0 = agent_ld(&hbuf[e + 0]);
            float v1 = agent_ld(&hbuf[e + 1]);
            float v2 = agent_ld(&hbuf[e + 2]);
            float v3 = agent_ld(&hbuf[e + 3]);
            float* p = &hsm[(e >> 5) * 33 + (e & 31)];
            p[0] = v0; p[1] = v1; p[2] = v2; p[3] = v3;
        }
        __syncthreads();

        float az = 0.f, ar = 0.f;
#pragma unroll
        for (int j = 0; j < 32; ++j) {
            float hj = hsm[cg * 33 + j];
            az = fmaf(uzw[j], hj, az);
            ar = fmaf(urw[j], hj, ar);
        }
#pragma unroll
        for (int mk = 8; mk; mk >>= 1) {
            az += __shfl_xor(az, mk);
            ar += __shfl_xor(ar, mk);
        }
        const float hrow = hsm[b * 33 + r];   // h[g] (padded index)
        const float zz = 1.f / (1.f + __expf(-(ezc + az + bzv)));
        const float rr = 1.f / (1.f + __expf(-(erc + ar + brv)));
        if (cg == 0) agent_st(&rhbuf[g], rr * hrow);
        __syncthreads();                       // all-wave vmcnt(0) drain
        if (tid == 0) flag_st(&flags[b * FSTRIDE], 2 * t + 1);
        if (tid < NB) { while (flag_ld(&flags[tid * FSTRIDE]) < 2 * t + 1) {} }
        __syncthreads();

        // ---- phase B: stage full r*h ----
        if (tid < 128) {
            const int e = tid * 4;
            float v0 = agent_ld(&rhbuf[e + 0]);
            float v1 = agent_ld(&rhbuf[e + 1]);
            float v2 = agent_ld(&rhbuf[e + 2]);
            float v3 = agent_ld(&rhbuf[e + 3]);
            float* p = &hsm[(e >> 5) * 33 + (e & 31)];
            p[0] = v0; p[1] = v1; p[2] = v2; p[3] = v3;
        }
        __syncthreads();

        float ah = 0.f;
#pragma unroll
        for (int j = 0; j < 32; ++j) {
            float xj = hsm[cg * 33 + j];
            ah = fmaf(uw[j], xj, ah);
        }
#pragma unroll
        for (int mk = 8; mk; mk >>= 1) ah += __shfl_xor(ah, mk);

        const float hxh  = tanhf(ehc + ah + bhv);
        const float hnew = hrow * zz + (1.f - zz) * hxh;
        if (cg == 0) {
            agent_st(&hbuf[g], hnew);
            outH[(size_t)t * D + g] = hnew;    // f32 hiddens output
        }
        __syncthreads();                       // all-wave vmcnt(0) drain
        if (tid == 0) flag_st(&flags[b * FSTRIDE], 2 * t + 2);
        if (tid < NB) { while (flag_ld(&flags[tid * FSTRIDE]) < 2 * t + 2) {} }
        __syncthreads();

        ezc = pz; erc = pr; ehc = ph;
    }
}

// ---------------------------------------------------------------------------
// logits GEMM (MFMA bf16): C[2048][32000] = hs * wy^T + by, f32 out.
// 128x128 tile, BK=64, 4 waves (2x2), 64x64/wave; f32->bf16 during staging.
// C/D layout (verified): col = lane&15, row = (lane>>4)*4 + q.
// ---------------------------------------------------------------------------
#define GBM 128
#define GBN 128
#define GBK 64

__global__ __launch_bounds__(256) void gemm_logits(
    const float* __restrict__ A,   // hs f32 [2048][512]
    const float* __restrict__ B,   // wy f32 [32000][512]
    const float* __restrict__ BY,  // by f32 [32000]
    float* __restrict__ C)         // logits f32 [2048][32000]
{
    __shared__ __align__(16) u16 As[GBM * GBK];
    __shared__ __align__(16) u16 Bs[GBN * GBK];

    const int tid = threadIdx.x;
    const int wv = tid >> 6, lane = tid & 63;
    const int lr = lane & 15, lg = lane >> 4;
    const int bm = blockIdx.y, bn = blockIdx.x;
    const int wm = (wv >> 1) * 64, wn = (wv & 1) * 64;

    const int srow = tid >> 3;        // 0..31 (row within 32-row pass)
    const int scol = (tid & 7) * 8;   // 0..56

    f32x4 acc[4][4] = {};

    for (int kt = 0; kt < D; kt += GBK) {
        __syncthreads();
#pragma unroll
        for (int p = 0; p < 4; ++p) {
            const int row = p * 32 + srow;
            f32x4 a0 = *(const f32x4*)&A[(size_t)(bm * GBM + row) * D + kt + scol];
            f32x4 a1 = *(const f32x4*)&A[(size_t)(bm * GBM + row) * D + kt + scol + 4];
            f32x4 b0 = *(const f32x4*)&B[(size_t)(bn * GBN + row) * D + kt + scol];
            f32x4 b1 = *(const f32x4*)&B[(size_t)(bn * GBN + row) * D + kt + scol + 4];
            us8 oa, ob;
#pragma unroll
            for (int q = 0; q < 4; ++q) {
                oa[q] = f2bf(a0[q]); oa[4 + q] = f2bf(a1[q]);
                ob[q] = f2bf(b0[q]); ob[4 + q] = f2bf(b1[q]);
            }
            *(us8*)&As[row * GBK + scol] = oa;
            *(us8*)&Bs[row * GBK + scol] = ob;
        }
        __syncthreads();
#pragma unroll
        for (int kk = 0; kk < 2; ++kk) {
            bf16x8 af[4], bfr[4];
#pragma unroll
            for (int mi = 0; mi < 4; ++mi)
                af[mi] = *(const bf16x8*)&As[(wm + mi * 16 + lr) * GBK + kk * 32 + lg * 8];
#pragma unroll
            for (int ni = 0; ni < 4; ++ni)
                bfr[ni] = *(const bf16x8*)&Bs[(wn + ni * 16 + lr) * GBK + kk * 32 + lg * 8];
#pragma unroll
            for (int mi = 0; mi < 4; ++mi)
#pragma unroll
                for (int ni = 0; ni < 4; ++ni)
                    acc[mi][ni] = __builtin_amdgcn_mfma_f32_16x16x32_bf16(
                        af[mi], bfr[ni], acc[mi][ni], 0, 0, 0);
        }
    }

#pragma unroll
    for (int ni = 0; ni < 4; ++ni) {
        const int n = bn * GBN + wn + ni * 16 + lr;
        const float byv = BY[n];
#pragma unroll
        for (int mi = 0; mi < 4; ++mi) {
#pragma unroll
            for (int q = 0; q < 4; ++q) {
                const int m = bm * GBM + wm + mi * 16 + lg * 4 + q;
                C[(size_t)m * VOCAB + n] = acc[mi][ni][q] + byv;
            }
        }
    }
}

// ---------------------------------------------------------------------------
// in-place log-softmax per row (f32); logits tiny (|x|<=7) so no max pass.
// ---------------------------------------------------------------------------
__global__ __launch_bounds__(256) void logsoftmax_kernel(float* __restrict__ C)
{
    const int m = blockIdx.x;
    float* row = C + (size_t)m * VOCAB;
    const int tid = threadIdx.x;

    float s = 0.f;
    for (int v = tid; v < VOCAB / 4; v += 256) {
        f32x4 x = *(const f32x4*)&row[v * 4];
        s += __expf(x[0]) + __expf(x[1]) + __expf(x[2]) + __expf(x[3]);
    }
#pragma unroll
    for (int mk = 32; mk; mk >>= 1) s += __shfl_xor(s, mk);
    __shared__ float red[4];
    if ((tid & 63) == 0) red[tid >> 6] = s;
    __syncthreads();
    const float lse = __logf(red[0] + red[1] + red[2] + red[3]);

    for (int v = tid; v < VOCAB / 4; v += 256) {
        f32x4 x = *(const f32x4*)&row[v * 4];
        x[0] -= lse; x[1] -= lse; x[2] -= lse; x[3] -= lse;
        *(f32x4*)&row[v * 4] = x;
    }
}

extern "C" void kernel_launch(void* const* d_in, const int* in_sizes, int n_in,
                              void* d_out, int out_size, void* d_ws, size_t ws_size,
                              hipStream_t stream)
{
    const int*   X  = (const int*)d_in[0];
    const float* wz = (const float*)d_in[1];
    const float* uz = (const float*)d_in[2];
    const float* w  = (const float*)d_in[3];
    const float* u  = (const float*)d_in[4];
    const float* wr = (const float*)d_in[5];
    const float* ur = (const float*)d_in[6];
    const float* wy = (const float*)d_in[7];
    const float* bz = (const float*)d_in[8];
    const float* br = (const float*)d_in[9];
    const float* bh = (const float*)d_in[10];
    const float* by = (const float*)d_in[11];

    float* out  = (float*)d_out;                     // outs f32 [2048][32000]
    float* outH = out + (size_t)SEQ * VOCAB;         // hiddens f32 [2048][512]

    // cross-block scratch: prefer d_ws; fall back to logits head (overwritten
    // by the GEMM later) if the workspace is unexpectedly small.
    char* scratch = (ws_size >= 8192) ? (char*)d_ws : (char*)d_out;
    int*   flags = (int*)scratch;                  // 1KB (16 x 64B lines)
    float* hbuf  = (float*)(scratch + 1024);       // 2KB
    float* rhbuf = (float*)(scratch + 3072);       // 2KB

    init_scratch<<<1, STPB, 0, stream>>>(flags, hbuf, rhbuf);

    scan_kernel<<<NB, STPB, 0, stream>>>(X, wz, uz, w, u, wr, ur, bz, br, bh,
                                         flags, hbuf, rhbuf, outH);

    dim3 ggrid(VOCAB / GBN, SEQ / GBM);            // (250, 16)
    gemm_logits<<<ggrid, 256, 0, stream>>>(outH, wy, by, out);

    logsoftmax_kernel<<<SEQ, 256, 0, stream>>>(out);
}

// Round 7
// 6843.425 us; speedup vs baseline: 3.7878x; 1.2202x over previous
//
#include <hip/hip_runtime.h>
#include <math.h>

typedef unsigned short u16;
typedef unsigned long long u64;
typedef unsigned short us8 __attribute__((ext_vector_type(8)));
typedef short bf16x8 __attribute__((ext_vector_type(8)));
typedef float f32x4 __attribute__((ext_vector_type(4)));

#define D       512
#define SEQ     2048
#define VOCAB   32000
#define NB      16      // scan blocks
#define RPB     32      // rows per block (512/16)
#define STPB    512     // scan threads per block

__device__ __forceinline__ u16 f2bf(float f) {   // round-to-nearest-even
    union { float f; unsigned i; } x; x.f = f;
    unsigned r = x.i + 0x7fff + ((x.i >> 16) & 1);
    return (u16)(r >> 16);
}

// tagged-value exchange: one 8B atom = (step_tag << 32) | f32 bits.
// relaxed agent-scope => LLC-coherent, no cache maintenance; tag+value are
// single-copy atomic so the poll hit IS the data read.
__device__ __forceinline__ u64 tag_ld(const u64* p) {
    return __hip_atomic_load(p, __ATOMIC_RELAXED, __HIP_MEMORY_SCOPE_AGENT);
}
__device__ __forceinline__ void tag_st(u64* p, u64 v) {
    __hip_atomic_store(p, v, __ATOMIC_RELAXED, __HIP_MEMORY_SCOPE_AGENT);
}
__device__ __forceinline__ u64 packtv(float f, unsigned tag) {
    union { float f; unsigned i; } x; x.f = f;
    return ((u64)tag << 32) | (u64)x.i;
}
__device__ __forceinline__ float unpackv(u64 v) {
    union { unsigned i; float f; } x; x.i = (unsigned)v;
    return x.f;
}

// ---------------------------------------------------------------------------
// zero the exchange buffers (tag 0 == h0 = 0.0f); runs every call/replay.
// ---------------------------------------------------------------------------
__global__ void init_scratch(u64* __restrict__ hbuf, u64* __restrict__ rhbuf)
{
    const int t = threadIdx.x;            // 512 threads, 1 block
    hbuf[t]  = 0ull;                      // value 0.0f, tag 0  (= h0, step-0 input)
    rhbuf[t] = 0ull;
}

// ---------------------------------------------------------------------------
// Persistent GRU scan: 16 blocks x 512 threads. Block b owns rows
// [32b, 32b+32) of uz, ur, u (f32 in registers, 96/thread). Per step t:
//   phase A: poll hbuf tags>=t -> LDS; compute z,r; write rhbuf tag t+1
//   phase B: poll rhbuf tags>=t+1 -> LDS; compute hxh, h_new; write hbuf
//            tag t+1 + f32 outH
// Tags are monotonic; the lockstep dependency structure guarantees no
// element is overwritten before all peers consumed the previous tag.
// ---------------------------------------------------------------------------
__global__ __launch_bounds__(STPB, 2) void scan_kernel(
    const int* __restrict__ X,
    const float* __restrict__ WZ, const float* __restrict__ UZ,
    const float* __restrict__ W,  const float* __restrict__ U,
    const float* __restrict__ WR, const float* __restrict__ UR,
    const float* __restrict__ BZ, const float* __restrict__ BR,
    const float* __restrict__ BH,
    u64* __restrict__ hbuf, u64* __restrict__ rhbuf,
    float* __restrict__ outH)
{
    __shared__ int   idxsm[SEQ];
    __shared__ float hsm[(D / 32) * 33];   // padded (stride 33) staging of h / rh

    const int tid = threadIdx.x, b = blockIdx.x;
    const int r  = tid >> 4;          // 0..31 local row
    const int cg = tid & 15;          // 0..15 column group
    const int c0 = cg * 32;
    const int g  = b * RPB + r;       // global row 0..511

    for (int i = tid; i < SEQ; i += STPB) idxsm[i] = X[i];

    // load weight slices (f32): 3 x 32 = 96 VGPRs
    float uzw[32], urw[32], uw[32];
#pragma unroll
    for (int j = 0; j < 32; j += 4) {
        f32x4 vz = *(const f32x4*)&UZ[(size_t)g * D + c0 + j];
        f32x4 vr = *(const f32x4*)&UR[(size_t)g * D + c0 + j];
        f32x4 vu = *(const f32x4*)&U [(size_t)g * D + c0 + j];
#pragma unroll
        for (int q = 0; q < 4; ++q) {
            uzw[j + q] = vz[q];
            urw[j + q] = vr[q];
            uw [j + q] = vu[q];
        }
    }
    const float bzv = BZ[g], brv = BR[g], bhv = BH[g];
    __syncthreads();

    // embedding pipeline: current-step values in regs, prefetch next
    const int i0 = idxsm[0];
    float ezc = WZ[(size_t)i0 * D + g];
    float erc = WR[(size_t)i0 * D + g];
    float ehc = W [(size_t)i0 * D + g];

#pragma unroll 1
    for (int t = 0; t < SEQ; ++t) {
        const int tn = (t + 1 < SEQ) ? t + 1 : t;
        const int in_ = idxsm[tn];
        const float pz = WZ[(size_t)in_ * D + g];
        const float pr = WR[(size_t)in_ * D + g];
        const float ph = W [(size_t)in_ * D + g];
        const unsigned ta = (unsigned)t;       // hbuf tag for this step's input
        const unsigned tb = (unsigned)t + 1u;  // rhbuf tag for this step

        // ---- phase A: poll full h (tag >= t) into LDS ----
        if (tid < 128) {
            const int e = tid * 4;
            u64 v0, v1, v2, v3;
            for (;;) {
                v0 = tag_ld(&hbuf[e + 0]);
                v1 = tag_ld(&hbuf[e + 1]);
                v2 = tag_ld(&hbuf[e + 2]);
                v3 = tag_ld(&hbuf[e + 3]);
                if ((unsigned)(v0 >> 32) >= ta && (unsigned)(v1 >> 32) >= ta &&
                    (unsigned)(v2 >> 32) >= ta && (unsigned)(v3 >> 32) >= ta)
                    break;
            }
            float* p = &hsm[(e >> 5) * 33 + (e & 31)];
            p[0] = unpackv(v0); p[1] = unpackv(v1);
            p[2] = unpackv(v2); p[3] = unpackv(v3);
        }
        __syncthreads();

        float az = 0.f, ar = 0.f;
#pragma unroll
        for (int j = 0; j < 32; ++j) {
            float hj = hsm[cg * 33 + j];
            az = fmaf(uzw[j], hj, az);
            ar = fmaf(urw[j], hj, ar);
        }
#pragma unroll
        for (int mk = 8; mk; mk >>= 1) {
            az += __shfl_xor(az, mk);
            ar += __shfl_xor(ar, mk);
        }
        const float hrow = hsm[b * 33 + r];   // h[g] (padded index)
        const float zz = 1.f / (1.f + __expf(-(ezc + az + bzv)));
        const float rr = 1.f / (1.f + __expf(-(erc + ar + brv)));
        if (cg == 0) tag_st(&rhbuf[g], packtv(rr * hrow, tb));
        __syncthreads();   // hsm reads done before phase B overwrites it

        // ---- phase B: poll full r*h (tag >= t+1) into LDS ----
        if (tid < 128) {
            const int e = tid * 4;
            u64 v0, v1, v2, v3;
            for (;;) {
                v0 = tag_ld(&rhbuf[e + 0]);
                v1 = tag_ld(&rhbuf[e + 1]);
                v2 = tag_ld(&rhbuf[e + 2]);
                v3 = tag_ld(&rhbuf[e + 3]);
                if ((unsigned)(v0 >> 32) >= tb && (unsigned)(v1 >> 32) >= tb &&
                    (unsigned)(v2 >> 32) >= tb && (unsigned)(v3 >> 32) >= tb)
                    break;
            }
            float* p = &hsm[(e >> 5) * 33 + (e & 31)];
            p[0] = unpackv(v0); p[1] = unpackv(v1);
            p[2] = unpackv(v2); p[3] = unpackv(v3);
        }
        __syncthreads();

        float ah = 0.f;
#pragma unroll
        for (int j = 0; j < 32; ++j) {
            float xj = hsm[cg * 33 + j];
            ah = fmaf(uw[j], xj, ah);
        }
#pragma unroll
        for (int mk = 8; mk; mk >>= 1) ah += __shfl_xor(ah, mk);

        const float hxh  = tanhf(ehc + ah + bhv);
        const float hnew = hrow * zz + (1.f - zz) * hxh;
        if (cg == 0) {
            tag_st(&hbuf[g], packtv(hnew, tb));   // next step's input, tag t+1
            outH[(size_t)t * D + g] = hnew;       // f32 hiddens output
        }
        __syncthreads();   // hsm reads done before next phase A overwrites it

        ezc = pz; erc = pr; ehc = ph;
    }
}

// ---------------------------------------------------------------------------
// logits GEMM (MFMA bf16): C[2048][32000] = hs * wy^T + by, f32 out.
// 128x128 tile, BK=64, 4 waves (2x2), 64x64/wave; f32->bf16 during staging.
// C/D layout (verified): col = lane&15, row = (lane>>4)*4 + q.
// ---------------------------------------------------------------------------
#define GBM 128
#define GBN 128
#define GBK 64

__global__ __launch_bounds__(256) void gemm_logits(
    const float* __restrict__ A,   // hs f32 [2048][512]
    const float* __restrict__ B,   // wy f32 [32000][512]
    const float* __restrict__ BY,  // by f32 [32000]
    float* __restrict__ C)         // logits f32 [2048][32000]
{
    __shared__ __align__(16) u16 As[GBM * GBK];
    __shared__ __align__(16) u16 Bs[GBN * GBK];

    const int tid = threadIdx.x;
    const int wv = tid >> 6, lane = tid & 63;
    const int lr = lane & 15, lg = lane >> 4;
    const int bm = blockIdx.y, bn = blockIdx.x;
    const int wm = (wv >> 1) * 64, wn = (wv & 1) * 64;

    const int srow = tid >> 3;        // 0..31 (row within 32-row pass)
    const int scol = (tid & 7) * 8;   // 0..56

    f32x4 acc[4][4] = {};

    for (int kt = 0; kt < D; kt += GBK) {
        __syncthreads();
#pragma unroll
        for (int p = 0; p < 4; ++p) {
            const int row = p * 32 + srow;
            f32x4 a0 = *(const f32x4*)&A[(size_t)(bm * GBM + row) * D + kt + scol];
            f32x4 a1 = *(const f32x4*)&A[(size_t)(bm * GBM + row) * D + kt + scol + 4];
            f32x4 b0 = *(const f32x4*)&B[(size_t)(bn * GBN + row) * D + kt + scol];
            f32x4 b1 = *(const f32x4*)&B[(size_t)(bn * GBN + row) * D + kt + scol + 4];
            us8 oa, ob;
#pragma unroll
            for (int q = 0; q < 4; ++q) {
                oa[q] = f2bf(a0[q]); oa[4 + q] = f2bf(a1[q]);
                ob[q] = f2bf(b0[q]); ob[4 + q] = f2bf(b1[q]);
            }
            *(us8*)&As[row * GBK + scol] = oa;
            *(us8*)&Bs[row * GBK + scol] = ob;
        }
        __syncthreads();
#pragma unroll
        for (int kk = 0; kk < 2; ++kk) {
            bf16x8 af[4], bfr[4];
#pragma unroll
            for (int mi = 0; mi < 4; ++mi)
                af[mi] = *(const bf16x8*)&As[(wm + mi * 16 + lr) * GBK + kk * 32 + lg * 8];
#pragma unroll
            for (int ni = 0; ni < 4; ++ni)
                bfr[ni] = *(const bf16x8*)&Bs[(wn + ni * 16 + lr) * GBK + kk * 32 + lg * 8];
#pragma unroll
            for (int mi = 0; mi < 4; ++mi)
#pragma unroll
                for (int ni = 0; ni < 4; ++ni)
                    acc[mi][ni] = __builtin_amdgcn_mfma_f32_16x16x32_bf16(
                        af[mi], bfr[ni], acc[mi][ni], 0, 0, 0);
        }
    }

#pragma unroll
    for (int ni = 0; ni < 4; ++ni) {
        const int n = bn * GBN + wn + ni * 16 + lr;
        const float byv = BY[n];
#pragma unroll
        for (int mi = 0; mi < 4; ++mi) {
#pragma unroll
            for (int q = 0; q < 4; ++q) {
                const int m = bm * GBM + wm + mi * 16 + lg * 4 + q;
                C[(size_t)m * VOCAB + n] = acc[mi][ni][q] + byv;
            }
        }
    }
}

// ---------------------------------------------------------------------------
// in-place log-softmax per row (f32); logits tiny (|x|<=7) so no max pass.
// ---------------------------------------------------------------------------
__global__ __launch_bounds__(256) void logsoftmax_kernel(float* __restrict__ C)
{
    const int m = blockIdx.x;
    float* row = C + (size_t)m * VOCAB;
    const int tid = threadIdx.x;

    float s = 0.f;
    for (int v = tid; v < VOCAB / 4; v += 256) {
        f32x4 x = *(const f32x4*)&row[v * 4];
        s += __expf(x[0]) + __expf(x[1]) + __expf(x[2]) + __expf(x[3]);
    }
#pragma unroll
    for (int mk = 32; mk; mk >>= 1) s += __shfl_xor(s, mk);
    __shared__ float red[4];
    if ((tid & 63) == 0) red[tid >> 6] = s;
    __syncthreads();
    const float lse = __logf(red[0] + red[1] + red[2] + red[3]);

    for (int v = tid; v < VOCAB / 4; v += 256) {
        f32x4 x = *(const f32x4*)&row[v * 4];
        x[0] -= lse; x[1] -= lse; x[2] -= lse; x[3] -= lse;
        *(f32x4*)&row[v * 4] = x;
    }
}

extern "C" void kernel_launch(void* const* d_in, const int* in_sizes, int n_in,
                              void* d_out, int out_size, void* d_ws, size_t ws_size,
                              hipStream_t stream)
{
    const int*   X  = (const int*)d_in[0];
    const float* wz = (const float*)d_in[1];
    const float* uz = (const float*)d_in[2];
    const float* w  = (const float*)d_in[3];
    const float* u  = (const float*)d_in[4];
    const float* wr = (const float*)d_in[5];
    const float* ur = (const float*)d_in[6];
    const float* wy = (const float*)d_in[7];
    const float* bz = (const float*)d_in[8];
    const float* br = (const float*)d_in[9];
    const float* bh = (const float*)d_in[10];
    const float* by = (const float*)d_in[11];

    float* out  = (float*)d_out;                     // outs f32 [2048][32000]
    float* outH = out + (size_t)SEQ * VOCAB;         // hiddens f32 [2048][512]

    // cross-block scratch: prefer d_ws; fall back to logits head (overwritten
    // by the GEMM later) if the workspace is unexpectedly small.
    char* scratch = (ws_size >= 8192) ? (char*)d_ws : (char*)d_out;
    u64* hbuf  = (u64*)scratch;                    // 4KB tagged h
    u64* rhbuf = (u64*)(scratch + 4096);           // 4KB tagged r*h

    init_scratch<<<1, STPB, 0, stream>>>(hbuf, rhbuf);

    scan_kernel<<<NB, STPB, 0, stream>>>(X, wz, uz, w, u, wr, ur, bz, br, bh,
                                         hbuf, rhbuf, outH);

    dim3 ggrid(VOCAB / GBN, SEQ / GBM);            // (250, 16)
    gemm_logits<<<ggrid, 256, 0, stream>>>(outH, wy, by, out);

    logsoftmax_kernel<<<SEQ, 256, 0, stream>>>(out);
}